// Round 2
// baseline (516.898 us; speedup 1.0000x reference)
//
#include <hip/hip_runtime.h>
#include <hip/hip_bf16.h>
#include <hip/hip_cooperative_groups.h>
#include <stdint.h>

namespace cg = cooperative_groups;

// ---------------------------------------------------------------------------
// AdaptiveDecision fused kernel, MI355X / gfx950  (round 4)
//
// Math (per row, B=32768, C=1024, CH=256):
//   h  = LN(x); d = h@Wd+bd; g = h@Wg+bg; h1 = d*sigmoid(g)
//   h1 = h1*dw_w + dw_b                      (folded into W1)
//   t  = gelu_tanh(h1@W1'+b1')
//   y  = t@Wcomb + bcomb
// LoRA right-fold: Wu" = Wu + (Wu@Wld)@Wlu ; bu" = bu + (bu@Wld)@Wlu
//   => Wcomb = W2@Wv@Wo@Wu" ; bias rides row 256 of the 272-row A chain.
//   out= 0.5*y + 0.5*x
//
// Round-4 change: ALL prep fused into ONE cooperative kernel (3 grid syncs):
//   stage0: weight packs + colsum partials + A0 + P1=[Wu;bu]@Wld  (363 blocks)
//   stageA: T1=A0@PWv  ||  Wu-fold->PWu/WUF  ||  bu2  ||  colsum reduce
//   stageB: T2=T1@PWo
//   stageC: PWc = pack(T2@PWu") direct via LDS ; bcomb = T2row256@WUF + bu2
// Replaces 6 serialized latency-bound launches (~270us) with 1 (~40-60us).
// ---------------------------------------------------------------------------

typedef float f32x4 __attribute__((ext_vector_type(4)));
typedef __bf16 bf16x8 __attribute__((ext_vector_type(8)));
typedef unsigned short u16x8 __attribute__((ext_vector_type(8)));
typedef unsigned short u16x4 __attribute__((ext_vector_type(4)));

#define LN_EPS 1e-5f

__device__ __forceinline__ unsigned short f2bf(float f) {
  unsigned int u = __float_as_uint(f);
  u += 0x7fffu + ((u >> 16) & 1u);          // RNE
  return (unsigned short)(u >> 16);
}

// barrier that does NOT drain vmcnt: LDS-visibility only.
__device__ __forceinline__ void bar_lds() {
  asm volatile("s_waitcnt lgkmcnt(0)\n\ts_barrier" ::: "memory");
}

// ---------------------------------------------------------------------------
// 16-row x 64-col chain-GEMM tile: C[16,64] += A[16rows,256] @ PB(packed).
// 4 waves, each wave one 16-col tile over K=256 (8 MFMAs). bias on row 256.
// b in 0..67: r0=(b>>2)*16 (17 row tiles), nt=(b&3)*4+w (16 col tiles).
// ---------------------------------------------------------------------------
__device__ __forceinline__ void gemm16x64(
    const float* __restrict__ A, const unsigned short* __restrict__ PB,
    float* __restrict__ C, const float* __restrict__ bias, int b, char* SMEM) {
  unsigned short* XA = (unsigned short*)SMEM;   // 512 u16
  const int tid = threadIdx.x;
  const int w = tid >> 6, l = tid & 63, q = l >> 4, m15 = l & 15;
  const int r0 = (b >> 2) * 16, nt = (b & 3) * 4 + w;
  const int srow = tid >> 4, kk = (tid & 15) * 2;
  const int xaidx = ((kk >> 3) * 16 + srow) * 8 + (kk & 7);
  const float* arow = A + (size_t)(r0 + srow) * 256 + kk;
  f32x4 acc = {0.f, 0.f, 0.f, 0.f};
  for (int kc = 0; kc < 8; ++kc) {
    float2 v = *(const float2*)(arow + kc * 32);
    XA[xaidx] = f2bf(v.x); XA[xaidx + 1] = f2bf(v.y);
    __syncthreads();
    bf16x8 af = *(const bf16x8*)&XA[l * 8];
    bf16x8 bf = *(const bf16x8*)(PB + ((size_t)(kc * 16 + nt) * 64 + l) * 8);
    acc = __builtin_amdgcn_mfma_f32_16x16x32_bf16(af, bf, acc, 0, 0, 0);
    __syncthreads();
  }
  const int col = nt * 16 + m15;
  #pragma unroll
  for (int r = 0; r < 4; ++r) {
    int grow = r0 + q * 4 + r;
    float vv = acc[r];
    if (grow == 256) vv += bias[col];
    C[(size_t)grow * 256 + col] = vv;
  }
}

// ---------------------------------------------------------------------------
// Cooperative prep kernel. grid = 363 blocks x 256 threads. LDS 32.9KB union.
// ---------------------------------------------------------------------------
__global__ __launch_bounds__(256) void k_prep_all(
    const float* __restrict__ ln_g, const float* __restrict__ ln_b,
    const float* __restrict__ Wd, const float* __restrict__ Wg,
    const float* __restrict__ dw_w, const float* __restrict__ dw_b,
    const float* __restrict__ W1, const float* __restrict__ b1,
    const float* __restrict__ W2, const float* __restrict__ b2,
    const float* __restrict__ Wv, const float* __restrict__ bv,
    const float* __restrict__ Wo, const float* __restrict__ bo,
    const float* __restrict__ Wu, const float* __restrict__ bu,
    const float* __restrict__ Wld, const float* __restrict__ Wlu,
    unsigned short* __restrict__ PGd, unsigned short* __restrict__ PGg,
    unsigned short* __restrict__ PW1, unsigned short* __restrict__ PWv,
    unsigned short* __restrict__ PWo, unsigned short* __restrict__ PWu,
    unsigned short* __restrict__ PWc,
    float* __restrict__ gdvA, float* __restrict__ ggvA,
    float* __restrict__ bdA, float* __restrict__ bgA,
    float* __restrict__ b1p, float* __restrict__ bcomb,
    float* __restrict__ A0, float* __restrict__ T1,
    float* __restrict__ WUF, float* __restrict__ P1,
    float* __restrict__ bu2, float* __restrict__ GP) {
  __shared__ alignas(16) char SMEM[32896];
  cg::grid_group grid = cg::this_grid();
  const int b = blockIdx.x, tid = threadIdx.x;

  // ===================== stage 0: independent prep ==========================
  if (b < 88) {
    // pack one 32-row K-chunk of a 256-col weight into B-frag layout
    float (*S)[257] = (float(*)[257])SMEM;      // exactly 32896B
    const float* src; const float* scale = nullptr; unsigned short* dst;
    int kc; int gpa = -1;
    if (b < 32)      { src = Wd; scale = ln_g; dst = PGd; kc = b;      gpa = 0; }
    else if (b < 64) { src = Wg; scale = ln_g; dst = PGg; kc = b - 32; gpa = 2; }
    else if (b < 72) { src = W1; scale = dw_w; dst = PW1; kc = b - 64; }
    else if (b < 80) { src = Wv; dst = PWv; kc = b - 72; }
    else             { src = Wo; dst = PWo; kc = b - 80; }
    float csg = 0.f, csb = 0.f;
    for (int r = 0; r < 32; ++r) {
      int k = kc * 32 + r;
      float raw = src[(size_t)k * 256 + tid];
      float v = scale ? scale[k] * raw : raw;
      S[r][tid] = v;
      if (gpa >= 0) { csg += v; csb += ln_b[k] * raw; }
    }
    if (gpa >= 0) {
      GP[((size_t)gpa * 32 + kc) * 256 + tid] = csg;
      GP[((size_t)(gpa + 1) * 32 + kc) * 256 + tid] = csb;
    }
    __syncthreads();
    const int ntL = tid >> 4;
    #pragma unroll
    for (int c = 0; c < 4; ++c) {
      int lane = (tid * 4 + c) & 63;
      int kb = (lane >> 4) * 8, nl = ntL * 16 + (lane & 15);
      u16x8 o;
      #pragma unroll
      for (int j = 0; j < 8; ++j) o[j] = f2bf(S[kb + j][nl]);
      *(u16x8*)(dst + ((size_t)(kc * 16 + ntL) * 64 + lane) * 8) = o;
    }
  } else if (b == 88) {
    float s = 0.f;
    for (int k = 0; k < 256; ++k) s += dw_b[k] * W1[k * 256 + tid];
    b1p[tid] = b1[tid] + s;
  } else if (b < 106) {
    int rb = b - 89;                        // 0..16: build A0 = [W2; b2; 0]
    for (int it = 0; it < 16; ++it) {
      int el = rb * 4096 + it * 256 + tid;  // < 272*256
      int row = el >> 8, col = el & 255;
      float v = (row < 256) ? W2[el] : ((row == 256) ? b2[col] : 0.f);
      A0[el] = v;
    }
  } else if (b < 363) {
    // P1[r] = (r<256 ? Wu[r] : bu) @ Wld     (257 rows, 1 block/row)
    float* RED = (float*)SMEM;              // 4096 f
    float* RED2 = RED + 4096;               // 256 f
    const int r = b - 106;
    const float* mrow = (r < 256) ? (Wu + (size_t)r * 1024) : bu;
    float p[16];
    #pragma unroll
    for (int c = 0; c < 16; ++c) p[c] = 0.f;
    #pragma unroll
    for (int k = 0; k < 4; ++k) {
      int n = tid + k * 256;
      float m = mrow[n];
      const float* wl = Wld + (size_t)n * 16;
      #pragma unroll
      for (int c = 0; c < 16; ++c) p[c] += m * wl[c];
    }
    #pragma unroll
    for (int c = 0; c < 16; ++c) RED[tid * 16 + c] = p[c];
    __syncthreads();
    {
      const int c = tid & 15, g2 = tid >> 4;
      float s = 0.f;
      #pragma unroll
      for (int i = 0; i < 16; ++i) s += RED[(g2 * 16 + i) * 16 + c];
      RED2[g2 * 16 + c] = s;
    }
    __syncthreads();
    if (tid < 16) {
      float s = 0.f;
      #pragma unroll
      for (int g3 = 0; g3 < 16; ++g3) s += RED2[g3 * 16 + tid];
      P1[r * 16 + tid] = s;
    }
  }
  grid.sync();

  // ===================== stage A ===========================================
  if (b < 68) {
    gemm16x64(A0, PWv, T1, bv, b, SMEM);          // T1 = A0 @ Wv (+bv row256)
  } else if (b < 132) {
    // fold: Wu"[32rows x 128cols] = Wu + P1@Wlu -> WUF f32 + PWu bf16 pack
    const int fb = b - 68, kcb = fb >> 3, ccol = (fb & 7) * 128;
    float* P1L = (float*)SMEM;                    // 512 f
    float* WL = P1L + 512;                        // 2048 f
    unsigned short* TL = (unsigned short*)(WL + 2048);  // 32*132 u16
    P1L[tid] = P1[(size_t)kcb * 512 + tid];
    P1L[tid + 256] = P1[(size_t)kcb * 512 + 256 + tid];
    #pragma unroll
    for (int i = 0; i < 8; ++i) {
      int el = tid + i * 256;                     // 0..2047
      int s = el >> 7, n = el & 127;
      WL[el] = Wlu[(size_t)s * 1024 + ccol + n];
    }
    __syncthreads();
    const int r = tid >> 3, c0 = (tid & 7) * 16;
    const float* wrow = Wu + (size_t)(kcb * 32 + r) * 1024 + ccol + c0;
    float acc[16];
    #pragma unroll
    for (int cc = 0; cc < 4; ++cc) {
      f32x4 wv = *(const f32x4*)(wrow + cc * 4);
      #pragma unroll
      for (int j = 0; j < 4; ++j) acc[cc * 4 + j] = wv[j];
    }
    #pragma unroll
    for (int s = 0; s < 16; ++s) {
      float m = P1L[r * 16 + s];
      #pragma unroll
      for (int c = 0; c < 16; ++c) acc[c] += m * WL[s * 128 + c0 + c];
    }
    float* wout = WUF + (size_t)(kcb * 32 + r) * 1024 + ccol + c0;
    #pragma unroll
    for (int cc = 0; cc < 4; ++cc) {
      f32x4 ov = {acc[cc * 4], acc[cc * 4 + 1], acc[cc * 4 + 2], acc[cc * 4 + 3]};
      *(f32x4*)(wout + cc * 4) = ov;
    }
    #pragma unroll
    for (int c = 0; c < 16; ++c) TL[r * 132 + c0 + c] = f2bf(acc[c]);
    __syncthreads();
    const int ntL = tid >> 5;
    #pragma unroll
    for (int hlf = 0; hlf < 2; ++hlf) {
      int lane = (tid & 31) + hlf * 32;
      int kb = (lane >> 4) * 8, nl = ntL * 16 + (lane & 15);
      u16x8 o;
      #pragma unroll
      for (int j = 0; j < 8; ++j) o[j] = TL[(kb + j) * 132 + nl];
      *(u16x8*)(PWu + ((size_t)(kcb * 64 + (fb & 7) * 8 + ntL) * 64 + lane) * 8) = o;
    }
  } else if (b == 132) {
    // bu2 = bu + P1[row256] @ Wlu
    float* s16 = (float*)SMEM;
    if (tid < 16) s16[tid] = P1[256 * 16 + tid];
    __syncthreads();
    #pragma unroll
    for (int c = 0; c < 4; ++c) {
      int n = tid + c * 256;
      float v = bu[n];
      #pragma unroll
      for (int s = 0; s < 16; ++s) v += s16[s] * Wlu[s * 1024 + n];
      bu2[n] = v;
    }
  } else if (b == 133) {
    // colsum partial reduce (replaces atomics+memset)
    float s0 = 0.f, s1 = 0.f, s2 = 0.f, s3 = 0.f;
    for (int kc2 = 0; kc2 < 32; ++kc2) {
      s0 += GP[((size_t)0 * 32 + kc2) * 256 + tid];
      s1 += GP[((size_t)1 * 32 + kc2) * 256 + tid];
      s2 += GP[((size_t)2 * 32 + kc2) * 256 + tid];
      s3 += GP[((size_t)3 * 32 + kc2) * 256 + tid];
    }
    gdvA[tid] = s0; bdA[tid] = s1; ggvA[tid] = s2; bgA[tid] = s3;
  }
  grid.sync();

  // ===================== stage B: T2 = T1 @ Wo (T2 aliases A0) =============
  if (b < 68) gemm16x64(T1, PWo, A0, bo, b, SMEM);
  grid.sync();

  // ===================== stage C: Wcomb tiles -> PWc ; bcomb ===============
  const float* T2 = A0;
  if (b < 128) {
    // 32 rows x 64 cols: rb = b>>4 (0..7), cg = b&15
    unsigned short* XA2 = (unsigned short*)SMEM;        // 2 x 1024 u16 dbuf
    unsigned short* TL = XA2 + 2048;                    // 32*68 u16
    const int rb = b >> 4, cg = b & 15;
    const int w = tid >> 6, l = tid & 63, q = l >> 4, m15 = l & 15;
    const int r0 = rb * 32;
    const int srow = tid >> 3;                          // 0..31
    const int kk = (tid & 7) * 4;                       // 0,4,..,28
    const int rt = srow >> 4, m = srow & 15;
    const int xaidx = rt * 512 + ((kk >> 3) * 16 + m) * 8 + (kk & 7);
    const float* arow = T2 + (size_t)(r0 + srow) * 256 + kk;
    f32x4 acc0 = {0.f, 0.f, 0.f, 0.f}, acc1 = {0.f, 0.f, 0.f, 0.f};
    float4 v = *(const float4*)arow;
    for (int kc = 0; kc < 8; ++kc) {
      unsigned short* xp = XA2 + (kc & 1) * 1024;
      u16x4 hv; hv[0] = f2bf(v.x); hv[1] = f2bf(v.y); hv[2] = f2bf(v.z); hv[3] = f2bf(v.w);
      *(u16x4*)&xp[xaidx] = hv;
      if (kc < 7) v = *(const float4*)(arow + (kc + 1) * 32);
      bar_lds();
      bf16x8 bf = *(const bf16x8*)(PWu + ((size_t)(kc * 64 + cg * 4 + w) * 64 + l) * 8);
      bf16x8 af0 = *(const bf16x8*)&xp[l * 8];
      bf16x8 af1 = *(const bf16x8*)&xp[512 + l * 8];
      acc0 = __builtin_amdgcn_mfma_f32_16x16x32_bf16(af0, bf, acc0, 0, 0, 0);
      acc1 = __builtin_amdgcn_mfma_f32_16x16x32_bf16(af1, bf, acc1, 0, 0, 0);
    }
    #pragma unroll
    for (int r = 0; r < 4; ++r) {
      TL[(q * 4 + r) * 68 + w * 16 + m15] = f2bf(acc0[r]);
      TL[(16 + q * 4 + r) * 68 + w * 16 + m15] = f2bf(acc1[r]);
    }
    bar_lds();
    const int ntL = tid >> 6, lane = tid & 63;
    const int kb = (lane >> 4) * 8, nl = ntL * 16 + (lane & 15);
    u16x8 o;
    #pragma unroll
    for (int j = 0; j < 8; ++j) o[j] = TL[(kb + j) * 68 + nl];
    *(u16x8*)(PWc + ((size_t)(rb * 64 + cg * 4 + ntL) * 64 + lane) * 8) = o;
  } else if (b < 144) {
    // bcomb[64 cols] = T2[256] @ WUF + bu2
    float* T2row = (float*)SMEM;            // 256 f
    float* PB4 = T2row + 256;               // 256 f
    const int c0 = (b - 128) * 64;
    T2row[tid] = T2[(size_t)256 * 256 + tid];
    __syncthreads();
    const int kpart = tid >> 6, cl = tid & 63, c = c0 + cl;
    float s = 0.f;
    for (int k = kpart * 64; k < kpart * 64 + 64; ++k)
      s += T2row[k] * WUF[(size_t)k * 1024 + c];
    PB4[kpart * 64 + cl] = s;
    __syncthreads();
    if (tid < 64)
      bcomb[c0 + tid] = PB4[tid] + PB4[64 + tid] + PB4[128 + tid] + PB4[192 + tid]
                        + bu2[c0 + tid];
  }
}

// ---------------------------------------------------------------------------
// Main fused kernel (unchanged from round 3). 512 blocks x 512 threads.
// Frag layouts: A[m=lane&15][k=(lane>>4)*8+j], B[k=(lane>>4)*8+j][n=lane&15],
// D[row=(lane>>4)*4+r][col=lane&15]
// ---------------------------------------------------------------------------
__global__ __launch_bounds__(512, 4) void k_main(
    const float* __restrict__ x,
    const unsigned short* __restrict__ PGd, const unsigned short* __restrict__ PGg,
    const unsigned short* __restrict__ PW1, const unsigned short* __restrict__ PWc,
    const float* __restrict__ gdvA, const float* __restrict__ ggvA,
    const float* __restrict__ bdA, const float* __restrict__ bgA,
    const float* __restrict__ bd, const float* __restrict__ bg,
    const float* __restrict__ b1p, const float* __restrict__ bcomb,
    float* __restrict__ out) {
  __shared__ unsigned short XA[2][2048];       // 8KB  dbuf A-frag staging
  __shared__ unsigned short HBUF[16384];       // 32KB h1 / t as A-frags
  __shared__ float SMS[1024];                  // 4KB  LN partials
  __shared__ float MURS[128];                  // mu, rs per row
  __shared__ float OBUF[16 * 260];             // 16.6KB output staging tile

  const int tid = threadIdx.x;
  const int w = tid >> 6, l = tid & 63, q = l >> 4, m15 = l & 15;
  const int row0 = blockIdx.x * 64;

  float gdc[2], ggc[2], bdc[2], bgc[2], b1c[2];
  #pragma unroll
  for (int i = 0; i < 2; ++i) {
    int col = w * 32 + i * 16 + m15;
    gdc[i] = gdvA[col]; ggc[i] = ggvA[col];
    bdc[i] = bdA[col] + bd[col];
    bgc[i] = bgA[col] + bg[col];
    b1c[i] = b1p[col];
  }

  // ---------------- stage 1: [64,1024] @ (Gd|Gg) ------------------------------
  f32x4 accd[4][2], accg[4][2];
  const f32x4 zero4 = {0.f, 0.f, 0.f, 0.f};
  #pragma unroll
  for (int mt = 0; mt < 4; ++mt)
    #pragma unroll
    for (int i = 0; i < 2; ++i) { accd[mt][i] = zero4; accg[mt][i] = zero4; }

  const int srow = tid >> 3, sseg = tid & 7;
  const float* xrow = x + (size_t)(row0 + srow) * 1024 + sseg * 4;
  const int xaidx = (((srow >> 4) * 64 + (sseg >> 1) * 16 + (srow & 15)) << 3) + (sseg & 1) * 4;
  float ssum = 0.f, ssq = 0.f;

  float4 v = *(const float4*)xrow;
  for (int kc = 0; kc < 32; ++kc) {
    const int p = kc & 1;
    u16x4 hv; hv[0] = f2bf(v.x); hv[1] = f2bf(v.y); hv[2] = f2bf(v.z); hv[3] = f2bf(v.w);
    *(u16x4*)&XA[p][xaidx] = hv;
    ssum += v.x + v.y + v.z + v.w;
    ssq += v.x * v.x + v.y * v.y + v.z * v.z + v.w * v.w;
    if (kc < 31) v = *(const float4*)(xrow + (kc + 1) * 32);   // prefetch (survives bar_lds)
    bar_lds();
    bf16x8 fd[2], fg[2];
    #pragma unroll
    for (int i = 0; i < 2; ++i) {
      size_t off = ((size_t)(kc * 16 + w * 2 + i) * 64 + l) * 8;
      fd[i] = *(const bf16x8*)(PGd + off);
      fg[i] = *(const bf16x8*)(PGg + off);
    }
    #pragma unroll
    for (int mt = 0; mt < 4; ++mt) {
      bf16x8 af = *(const bf16x8*)&XA[p][(mt * 64 + l) * 8];
      #pragma unroll
      for (int i = 0; i < 2; ++i) {
        accd[mt][i] = __builtin_amdgcn_mfma_f32_16x16x32_bf16(af, fd[i], accd[mt][i], 0, 0, 0);
        accg[mt][i] = __builtin_amdgcn_mfma_f32_16x16x32_bf16(af, fg[i], accg[mt][i], 0, 0, 0);
      }
    }
  }

  // LN statistics (8 partials/row)
  SMS[tid] = ssum;
  SMS[512 + tid] = ssq;
  bar_lds();
  if (tid < 64) {
    float s = 0.f, sq = 0.f;
    #pragma unroll
    for (int p2 = 0; p2 < 8; ++p2) { s += SMS[tid * 8 + p2]; sq += SMS[512 + tid * 8 + p2]; }
    float mu = s * (1.f / 1024.f);
    float var = sq * (1.f / 1024.f) - mu * mu;
    MURS[tid * 2] = mu;
    MURS[tid * 2 + 1] = rsqrtf(var + LN_EPS);
  }
  bar_lds();

  // stage-1 epilogue: LN correction + GLU gate -> h1 bf16 in HBUF (A-frag order)
  #pragma unroll
  for (int i = 0; i < 2; ++i) {
    int q2 = i * 2 + (m15 >> 3), j2 = m15 & 7;
    #pragma unroll
    for (int mt = 0; mt < 4; ++mt) {
      #pragma unroll
      for (int r = 0; r < 4; ++r) {
        int row = mt * 16 + q * 4 + r;
        float mu = MURS[row * 2], rs = MURS[row * 2 + 1];
        float pd = rs * (accd[mt][i][r] - mu * gdc[i]) + bdc[i];
        float pg = rs * (accg[mt][i][r] - mu * ggc[i]) + bgc[i];
        float hv = pd / (1.f + __expf(-pg));
        HBUF[((mt * 8 + w) * 64 + q2 * 16 + q * 4 + r) * 8 + j2] = f2bf(hv);
      }
    }
  }
  bar_lds();

  // ---------------- stage 2: t = gelu(h1 @ W1' + b1') ------------------------
  f32x4 acc2[4][2];
  #pragma unroll
  for (int mt = 0; mt < 4; ++mt)
    #pragma unroll
    for (int i = 0; i < 2; ++i) acc2[mt][i] = zero4;
  for (int kc = 0; kc < 8; ++kc) {
    bf16x8 bf[2];
    #pragma unroll
    for (int i = 0; i < 2; ++i)
      bf[i] = *(const bf16x8*)(PW1 + ((size_t)(kc * 16 + w * 2 + i) * 64 + l) * 8);
    #pragma unroll
    for (int mt = 0; mt < 4; ++mt) {
      bf16x8 af = *(const bf16x8*)&HBUF[((mt * 8 + kc) * 64 + l) * 8];
      #pragma unroll
      for (int i = 0; i < 2; ++i)
        acc2[mt][i] = __builtin_amdgcn_mfma_f32_16x16x32_bf16(af, bf[i], acc2[mt][i], 0, 0, 0);
    }
  }
  bar_lds();   // all reads of h1 done before overwrite with t
  #pragma unroll
  for (int i = 0; i < 2; ++i) {
    int q2 = i * 2 + (m15 >> 3), j2 = m15 & 7;
    #pragma unroll
    for (int mt = 0; mt < 4; ++mt) {
      #pragma unroll
      for (int r = 0; r < 4; ++r) {
        float vv = acc2[mt][i][r] + b1c[i];
        float u = 0.7978845608f * (vv + 0.044715f * vv * vv * vv);
        float th = 1.f - 2.f / (1.f + __expf(2.f * u));
        HBUF[((mt * 8 + w) * 64 + q2 * 16 + q * 4 + r) * 8 + j2] = f2bf(0.5f * vv * (1.f + th));
      }
    }
  }
  bar_lds();

  // ---------------- stage 3: y = t @ Wcomb + bcomb; out = 0.5y + 0.5x --------
  for (int nc = 0; nc < 4; ++nc) {
    f32x4 acc3[4][2];
    #pragma unroll
    for (int mt = 0; mt < 4; ++mt)
      #pragma unroll
      for (int i = 0; i < 2; ++i) acc3[mt][i] = zero4;
    for (int kc = 0; kc < 8; ++kc) {
      bf16x8 bf[2];
      #pragma unroll
      for (int i = 0; i < 2; ++i)
        bf[i] = *(const bf16x8*)(PWc + ((size_t)(kc * 64 + nc * 16 + w * 2 + i) * 64 + l) * 8);
      #pragma unroll
      for (int mt = 0; mt < 4; ++mt) {
        bf16x8 af = *(const bf16x8*)&HBUF[((mt * 8 + kc) * 64 + l) * 8];
        #pragma unroll
        for (int i = 0; i < 2; ++i)
          acc3[mt][i] = __builtin_amdgcn_mfma_f32_16x16x32_bf16(af, bf[i], acc3[mt][i], 0, 0, 0);
      }
    }
    float bc[2];
    #pragma unroll
    for (int i = 0; i < 2; ++i) bc[i] = bcomb[nc * 256 + w * 32 + i * 16 + m15];
    // stage through OBUF per 16-row tile for coalesced float4 out writes
    const int rowL = tid >> 5, c0 = (tid & 31) * 4;
    #pragma unroll
    for (int mt = 0; mt < 4; ++mt) {
      #pragma unroll
      for (int r = 0; r < 4; ++r)
        #pragma unroll
        for (int i = 0; i < 2; ++i)
          OBUF[(q * 4 + r) * 260 + w * 32 + i * 16 + m15] = acc3[mt][i][r] + bc[i];
      bar_lds();
      const size_t gbase = (size_t)(row0 + mt * 16 + rowL) * 1024 + nc * 256;
      #pragma unroll
      for (int h = 0; h < 2; ++h) {
        int cc = c0 + h * 128;
        f32x4 yv = *(const f32x4*)&OBUF[rowL * 260 + cc];
        float4 xr = *(const float4*)(x + gbase + cc);
        float4 o;
        o.x = 0.5f * yv[0] + 0.5f * xr.x;
        o.y = 0.5f * yv[1] + 0.5f * xr.y;
        o.z = 0.5f * yv[2] + 0.5f * xr.z;
        o.w = 0.5f * yv[3] + 0.5f * xr.w;
        *(float4*)(out + gbase + cc) = o;
      }
      bar_lds();
    }
  }
}

// ---------------------------------------------------------------------------
extern "C" void kernel_launch(void* const* d_in, const int* in_sizes, int n_in,
                              void* d_out, int out_size, void* d_ws, size_t ws_size,
                              hipStream_t stream) {
  (void)in_sizes; (void)n_in; (void)out_size; (void)ws_size;
  const float* x    = (const float*)d_in[0];
  const float* ln_g = (const float*)d_in[1];
  const float* ln_b = (const float*)d_in[2];
  const float* Wd   = (const float*)d_in[3];
  const float* bd   = (const float*)d_in[4];
  const float* Wg   = (const float*)d_in[5];
  const float* bg   = (const float*)d_in[6];
  const float* dw_w = (const float*)d_in[7];
  const float* dw_b = (const float*)d_in[8];
  const float* W1   = (const float*)d_in[9];
  const float* b1   = (const float*)d_in[10];
  const float* W2   = (const float*)d_in[11];
  const float* b2   = (const float*)d_in[12];
  // d_in[13..16] = Wq,bq,Wk,bk : dead code (softmax over 1 key == 1)
  const float* Wv   = (const float*)d_in[17];
  const float* bv   = (const float*)d_in[18];
  const float* Wo   = (const float*)d_in[19];
  const float* bo   = (const float*)d_in[20];
  const float* Wu   = (const float*)d_in[21];
  const float* bu   = (const float*)d_in[22];
  const float* Wld  = (const float*)d_in[23];
  const float* Wlu  = (const float*)d_in[24];
  float* out = (float*)d_out;

  char* ws = (char*)d_ws;
  unsigned short* PGd = (unsigned short*)(ws + 0);         // 512KB
  unsigned short* PGg = (unsigned short*)(ws + 524288);    // 512KB
  unsigned short* PW1 = (unsigned short*)(ws + 1048576);   // 128KB
  unsigned short* PWv = (unsigned short*)(ws + 1179648);   // 128KB
  unsigned short* PWo = (unsigned short*)(ws + 1310720);   // 128KB
  unsigned short* PWu = (unsigned short*)(ws + 1441792);   // 512KB
  unsigned short* PWc = (unsigned short*)(ws + 1966080);   // 512KB
  float* gdvA  = (float*)(ws + 2490368);                   // 1KB
  float* ggvA  = (float*)(ws + 2491392);                   // 1KB
  float* bdA   = (float*)(ws + 2492416);                   // 1KB
  float* bgA   = (float*)(ws + 2493440);                   // 1KB
  float* b1p   = (float*)(ws + 2494464);                   // 1KB
  float* bcomb = (float*)(ws + 2495488);                   // 4KB
  float* A0    = (float*)(ws + 2499584);                   // 272x256 f32; also T2
  float* T1    = (float*)(ws + 2778112);                   // 272x256 f32
  float* WUF   = (float*)(ws + 3056640);                   // 256x1024 f32 -> 4105216
  float* bu2   = (float*)(ws + 4105216);                   // 4KB -> 4109312
  // GP (colsum partials, 128KB) + P1 (257x16 f32) alias PWc: written stage0,
  // read stageA, dead before stageC writes PWc.
  float* GP    = (float*)(ws + 1966080);
  float* P1    = (float*)(ws + 1966080 + 131072);

  void* args[] = {
      (void*)&ln_g, (void*)&ln_b, (void*)&Wd, (void*)&Wg,
      (void*)&dw_w, (void*)&dw_b, (void*)&W1, (void*)&b1,
      (void*)&W2, (void*)&b2, (void*)&Wv, (void*)&bv,
      (void*)&Wo, (void*)&bo, (void*)&Wu, (void*)&bu,
      (void*)&Wld, (void*)&Wlu,
      (void*)&PGd, (void*)&PGg, (void*)&PW1, (void*)&PWv,
      (void*)&PWo, (void*)&PWu, (void*)&PWc,
      (void*)&gdvA, (void*)&ggvA, (void*)&bdA, (void*)&bgA,
      (void*)&b1p, (void*)&bcomb,
      (void*)&A0, (void*)&T1, (void*)&WUF, (void*)&P1,
      (void*)&bu2, (void*)&GP};
  hipLaunchCooperativeKernel((const void*)k_prep_all, dim3(363), dim3(256),
                             args, 0, stream);
  hipLaunchKernelGGL(k_main, dim3(512), dim3(512), 0, stream,
                     x, PGd, PGg, PW1, PWc, gdvA, ggvA, bdA, bgA, bd, bg, b1p, bcomb, out);
}

// Round 4
// 457.370 us; speedup vs baseline: 1.1302x; 1.1302x over previous
//
#include <hip/hip_runtime.h>
#include <hip/hip_bf16.h>
#include <stdint.h>

// ---------------------------------------------------------------------------
// AdaptiveDecision fused kernel, MI355X / gfx950  (round 6 = round-5 resubmit,
// dead PX pack removed; round-5 bench was an infra failure, no counters)
//
// Math (per row, B=32768, C=1024, CH=256):
//   h  = LN(x); d = h@Wd+bd; g = h@Wg+bg; h1 = d*sigmoid(g)
//   h1 = h1*dw_w + dw_b                      (folded into W1)
//   t  = gelu_tanh(h1@W1'+b1')
//   y  = t@Wcomb + bcomb ;  out = 0.5*y + 0.5*x
//
// Binary-tree chain:  Wcomb = W2@Wv@Wo@Wu@(I+Wld@Wlu) = X @ Y'''
//   L1 k_prep  (input-only, 154 blk): packs PGd/PGg/PW1 + colsum partials +
//              b1p + X=W2@Wv (f32) + Y=Wo@Wu (f32) + full bias chain bcomb
//   L2 k_fold  (65 blk): Y''' = Y + (Y@Wld)@Wlu -> PY pack ; colsum reduce
//   L3 k_wcomb (128 blk): PWc = pack_bf16(X @ PY) via MFMA
//   k_main unchanged (verified round-3 kernel, ~130us).
// vs round-3: 3 prep launches instead of 6 (+memset); no atomics; Wcomb goes
// through ONE bf16 GEMM instead of three (X,Y,Y''' are f32).
// ---------------------------------------------------------------------------

typedef float f32x4 __attribute__((ext_vector_type(4)));
typedef __bf16 bf16x8 __attribute__((ext_vector_type(8)));
typedef unsigned short u16x8 __attribute__((ext_vector_type(8)));
typedef unsigned short u16x4 __attribute__((ext_vector_type(4)));

#define LN_EPS 1e-5f

__device__ __forceinline__ unsigned short f2bf(float f) {
  unsigned int u = __float_as_uint(f);
  u += 0x7fffu + ((u >> 16) & 1u);          // RNE
  return (unsigned short)(u >> 16);
}

// barrier that does NOT drain vmcnt: LDS-visibility only.
__device__ __forceinline__ void bar_lds() {
  asm volatile("s_waitcnt lgkmcnt(0)\n\ts_barrier" ::: "memory");
}

// ---------------------------------------------------------------------------
// L1: all input-only prep in one wide launch (154 blocks x 256 threads).
//  0-31  : pack ln_g.*Wd -> PGd  (+ GP colsum partial planes 0,1)
//  32-63 : pack ln_g.*Wg -> PGg  (+ GP planes 2,3)
//  64-71 : pack dw_w.*W1 -> PW1
//  72    : b1p = b1 + dw_b@W1
//  73    : bias chain: r1=b2@Wv+bv; r2=r1@Wo+bo; r3=r2@Wu+bu;
//          bcomb = r3 + (r3@Wld)@Wlu        (all inputs only)
//  74-89 : X = W2@Wv   (f32, 16 blocks x 16 rows)
//  90-153: Y = Wo@Wu   (f32, 64 blocks: 16 rows x 256 cols)
// Packed B-frag layout: P[((kc*NT+nt)*64+lane)*8+j] = W[kc*32+(lane>>4)*8+j][nt*16+(lane&15)]
// ---------------------------------------------------------------------------
__global__ __launch_bounds__(256) void k_prep(
    const float* __restrict__ ln_g, const float* __restrict__ ln_b,
    const float* __restrict__ Wd, const float* __restrict__ Wg,
    const float* __restrict__ dw_w, const float* __restrict__ dw_b,
    const float* __restrict__ W1, const float* __restrict__ b1,
    const float* __restrict__ W2, const float* __restrict__ b2,
    const float* __restrict__ Wv, const float* __restrict__ bv,
    const float* __restrict__ Wo, const float* __restrict__ bo,
    const float* __restrict__ Wu, const float* __restrict__ bu,
    const float* __restrict__ Wld, const float* __restrict__ Wlu,
    unsigned short* __restrict__ PGd, unsigned short* __restrict__ PGg,
    unsigned short* __restrict__ PW1, float* __restrict__ GP,
    float* __restrict__ b1p, float* __restrict__ X,
    float* __restrict__ Y, float* __restrict__ bcomb) {
  __shared__ alignas(16) char SMEM[32896];
  const int b = blockIdx.x, tid = threadIdx.x;

  if (b < 72) {
    // ---- pack one 32-row K-chunk of a 256-col weight into B-frag layout ----
    float (*S)[257] = (float(*)[257])SMEM;      // 32x257 f = 32896B
    const float* src; const float* scale; unsigned short* dst;
    int kc; int gpa = -1;
    if (b < 32)      { src = Wd; scale = ln_g; dst = PGd; kc = b;      gpa = 0; }
    else if (b < 64) { src = Wg; scale = ln_g; dst = PGg; kc = b - 32; gpa = 2; }
    else             { src = W1; scale = dw_w; dst = PW1; kc = b - 64; }
    float csg = 0.f, csb = 0.f;
    for (int r = 0; r < 32; ++r) {
      int k = kc * 32 + r;
      float raw = src[(size_t)k * 256 + tid];
      float v = scale[k] * raw;
      S[r][tid] = v;
      if (gpa >= 0) { csg += v; csb += ln_b[k] * raw; }
    }
    if (gpa >= 0) {
      GP[((size_t)gpa * 32 + kc) * 256 + tid] = csg;
      GP[((size_t)(gpa + 1) * 32 + kc) * 256 + tid] = csb;
    }
    __syncthreads();
    const int ntL = tid >> 4;
    #pragma unroll
    for (int c = 0; c < 4; ++c) {
      int lane = (tid * 4 + c) & 63;
      int kb = (lane >> 4) * 8, nl = ntL * 16 + (lane & 15);
      u16x8 o;
      #pragma unroll
      for (int j = 0; j < 8; ++j) o[j] = f2bf(S[kb + j][nl]);
      *(u16x8*)(dst + ((size_t)(kc * 16 + ntL) * 64 + lane) * 8) = o;
    }
  } else if (b == 72) {
    float s = 0.f;
    #pragma unroll 8
    for (int k = 0; k < 256; ++k) s += dw_b[k] * W1[k * 256 + tid];
    b1p[tid] = b1[tid] + s;
  } else if (b == 73) {
    // ---- full bias chain, one block ----
    float* F = (float*)SMEM;
    float* r1 = F;            // 256
    float* r2 = F + 256;      // 256
    float* r3 = F + 512;      // 1024
    float* s16 = F + 1536;    // 16
    float* PART = F + 1552;   // 256
    float* sb = F + 1808;     // 256 (b2 staged)
    sb[tid] = b2[tid];
    __syncthreads();
    {
      float s = bv[tid];
      #pragma unroll 8
      for (int k = 0; k < 256; ++k) s += sb[k] * Wv[(size_t)k * 256 + tid];
      r1[tid] = s;
    }
    __syncthreads();
    {
      float s = bo[tid];
      #pragma unroll 8
      for (int k = 0; k < 256; ++k) s += r1[k] * Wo[(size_t)k * 256 + tid];
      r2[tid] = s;
    }
    __syncthreads();
    {
      float a0 = bu[tid], a1 = bu[tid + 256], a2 = bu[tid + 512], a3 = bu[tid + 768];
      #pragma unroll 4
      for (int k = 0; k < 256; ++k) {
        float rr = r2[k];
        const float* wr = Wu + (size_t)k * 1024 + tid;
        a0 += rr * wr[0]; a1 += rr * wr[256]; a2 += rr * wr[512]; a3 += rr * wr[768];
      }
      r3[tid] = a0; r3[tid + 256] = a1; r3[tid + 512] = a2; r3[tid + 768] = a3;
    }
    __syncthreads();
    {
      const int g = tid >> 4, s = tid & 15;
      float p = 0.f;
      #pragma unroll 4
      for (int n = g * 64; n < g * 64 + 64; ++n) p += r3[n] * Wld[(size_t)n * 16 + s];
      PART[g * 16 + s] = p;
    }
    __syncthreads();
    if (tid < 16) {
      float s = 0.f;
      #pragma unroll
      for (int g = 0; g < 16; ++g) s += PART[g * 16 + tid];
      s16[tid] = s;
    }
    __syncthreads();
    #pragma unroll
    for (int c = 0; c < 4; ++c) {
      int n = tid + c * 256;
      float v = r3[n];
      #pragma unroll
      for (int s = 0; s < 16; ++s) v += s16[s] * Wlu[(size_t)s * 1024 + n];
      bcomb[n] = v;
    }
  } else if (b < 90) {
    // ---- X = W2@Wv, 16 rows/block ----
    float (*SW)[257] = (float(*)[257])SMEM;
    const int r0 = (b - 74) * 16;
    #pragma unroll
    for (int r = 0; r < 16; ++r) SW[r][tid] = W2[(size_t)(r0 + r) * 256 + tid];
    __syncthreads();
    float acc[16];
    #pragma unroll
    for (int r = 0; r < 16; ++r) acc[r] = 0.f;
    #pragma unroll 4
    for (int n = 0; n < 256; ++n) {
      float wv = Wv[(size_t)n * 256 + tid];
      #pragma unroll
      for (int r = 0; r < 16; ++r) acc[r] += SW[r][n] * wv;
    }
    #pragma unroll
    for (int r = 0; r < 16; ++r) X[(size_t)(r0 + r) * 256 + tid] = acc[r];
  } else {
    // ---- Y = Wo@Wu, 16 rows x 256 cols per block ----
    float (*SW)[257] = (float(*)[257])SMEM;
    const int idx = b - 90, r0 = (idx >> 2) * 16, c0 = (idx & 3) * 256;
    #pragma unroll
    for (int r = 0; r < 16; ++r) SW[r][tid] = Wo[(size_t)(r0 + r) * 256 + tid];
    __syncthreads();
    float acc[16];
    #pragma unroll
    for (int r = 0; r < 16; ++r) acc[r] = 0.f;
    #pragma unroll 4
    for (int n = 0; n < 256; ++n) {
      float wu = Wu[(size_t)n * 1024 + c0 + tid];
      #pragma unroll
      for (int r = 0; r < 16; ++r) acc[r] += SW[r][n] * wu;
    }
    #pragma unroll
    for (int r = 0; r < 16; ++r) Y[(size_t)(r0 + r) * 1024 + c0 + tid] = acc[r];
  }
}

// ---------------------------------------------------------------------------
// L2: k_fold (65 blocks).
//  b<64 : rb=b>>3 (32-row slab), ccol=(b&7)*128. In-block YL = Yslab@Wld,
//         then Y'''tile = Y + YL@Wlu, pack -> PY.
//  64   : reduce GP partials -> gdvA/bdA/ggvA/bgA
// ---------------------------------------------------------------------------
__global__ __launch_bounds__(256) void k_fold(
    const float* __restrict__ Y, const float* __restrict__ Wld,
    const float* __restrict__ Wlu, const float* __restrict__ GP,
    unsigned short* __restrict__ PY,
    float* __restrict__ gdvA, float* __restrict__ ggvA,
    float* __restrict__ bdA, float* __restrict__ bgA) {
  __shared__ alignas(16) char SMEM[32896];
  const int b = blockIdx.x, tid = threadIdx.x;
  if (b < 64) {
    float* F = (float*)SMEM;
    float* YLL = F;                          // 512 f  [32][16]
    float* WL = F + 512;                     // 2048 f [16][128]
    float* PART = F + 2560;                  // 4096 f [32*16][8]
    // TL overlaps PART in bytes but PART is dead before TL is written
    // (separated by __syncthreads).
    unsigned short* TL = (unsigned short*)(SMEM + 10240);  // 32x132 u16
    const int rb = b >> 3, ccol = (b & 7) * 128;
    // phase A: YL[32][16] = Yslab @ Wld (n split 8 ways)
    {
      const int r = tid >> 3, g = tid & 7;
      const float* yrow = Y + (size_t)(rb * 32 + r) * 1024;
      float p[16];
      #pragma unroll
      for (int s = 0; s < 16; ++s) p[s] = 0.f;
      for (int n = g * 128; n < g * 128 + 128; ++n) {
        float yv = yrow[n];
        const float* wl = Wld + (size_t)n * 16;
        #pragma unroll
        for (int s = 0; s < 16; ++s) p[s] += yv * wl[s];
      }
      #pragma unroll
      for (int s = 0; s < 16; ++s) PART[(r * 16 + s) * 8 + g] = p[s];
    }
    __syncthreads();
    #pragma unroll
    for (int e2 = 0; e2 < 2; ++e2) {
      int e = tid + e2 * 256;
      float s = 0.f;
      #pragma unroll
      for (int g = 0; g < 8; ++g) s += PART[e * 8 + g];
      YLL[e] = s;
    }
    // phase B: load Wlu chunk [16][128]
    #pragma unroll
    for (int i = 0; i < 8; ++i) {
      int el = tid + i * 256;
      int s = el >> 7, n = el & 127;
      WL[el] = Wlu[(size_t)s * 1024 + ccol + n];
    }
    __syncthreads();
    // Y''' tile = Y + YL@Wlu ; -> TL bf16
    const int r = tid >> 3, c0 = (tid & 7) * 16;
    const float* yrow = Y + (size_t)(rb * 32 + r) * 1024 + ccol + c0;
    float acc[16];
    #pragma unroll
    for (int cc = 0; cc < 4; ++cc) {
      f32x4 yv = *(const f32x4*)(yrow + cc * 4);
      #pragma unroll
      for (int j = 0; j < 4; ++j) acc[cc * 4 + j] = yv[j];
    }
    #pragma unroll
    for (int s = 0; s < 16; ++s) {
      float m = YLL[r * 16 + s];
      #pragma unroll
      for (int c = 0; c < 16; ++c) acc[c] += m * WL[s * 128 + c0 + c];
    }
    #pragma unroll
    for (int c = 0; c < 16; ++c) TL[r * 132 + c0 + c] = f2bf(acc[c]);
    __syncthreads();
    // pack -> PY (NT=64)
    const int ntL = tid >> 5;
    #pragma unroll
    for (int hlf = 0; hlf < 2; ++hlf) {
      int lane = (tid & 31) + hlf * 32;
      int kb = (lane >> 4) * 8, nl = ntL * 16 + (lane & 15);
      u16x8 o;
      #pragma unroll
      for (int j = 0; j < 8; ++j) o[j] = TL[(kb + j) * 132 + nl];
      *(u16x8*)(PY + ((size_t)(rb * 64 + (b & 7) * 8 + ntL) * 64 + lane) * 8) = o;
    }
  } else {
    // colsum partial reduce
    float s0 = 0.f, s1 = 0.f, s2 = 0.f, s3 = 0.f;
    for (int kc2 = 0; kc2 < 32; ++kc2) {
      s0 += GP[((size_t)0 * 32 + kc2) * 256 + tid];
      s1 += GP[((size_t)1 * 32 + kc2) * 256 + tid];
      s2 += GP[((size_t)2 * 32 + kc2) * 256 + tid];
      s3 += GP[((size_t)3 * 32 + kc2) * 256 + tid];
    }
    gdvA[tid] = s0; bdA[tid] = s1; ggvA[tid] = s2; bgA[tid] = s3;
  }
}

// ---------------------------------------------------------------------------
// L3: k_wcomb (128 blocks): PWc = pack_bf16(X @ PY).  32 rows x 64 cols per
// block: rb=b>>4 (8 row slabs of 32), cg=b&15 (16 col groups of 64).
// On-the-fly A pack from f32 X (verified round-4 stage-C structure).
// ---------------------------------------------------------------------------
__global__ __launch_bounds__(256) void k_wcomb(
    const float* __restrict__ X, const unsigned short* __restrict__ PY,
    unsigned short* __restrict__ PWc) {
  __shared__ alignas(16) char SMEM[32896];
  unsigned short* XA2 = (unsigned short*)SMEM;        // 2 x 1024 u16 dbuf
  unsigned short* TL = XA2 + 2048;                    // 32x68 u16
  const int b = blockIdx.x, tid = threadIdx.x;
  const int rb = b >> 4, cg = b & 15;
  const int w = tid >> 6, l = tid & 63, q = l >> 4, m15 = l & 15;
  const int r0 = rb * 32;
  const int srow = tid >> 3;                          // 0..31
  const int kk = (tid & 7) * 4;                       // 0,4,..,28
  const int rt = srow >> 4, m = srow & 15;
  const int xaidx = rt * 512 + ((kk >> 3) * 16 + m) * 8 + (kk & 7);
  const float* arow = X + (size_t)(r0 + srow) * 256 + kk;
  f32x4 acc0 = {0.f, 0.f, 0.f, 0.f}, acc1 = {0.f, 0.f, 0.f, 0.f};
  float4 v = *(const float4*)arow;
  for (int kc = 0; kc < 8; ++kc) {
    unsigned short* xp = XA2 + (kc & 1) * 1024;
    u16x4 hv; hv[0] = f2bf(v.x); hv[1] = f2bf(v.y); hv[2] = f2bf(v.z); hv[3] = f2bf(v.w);
    *(u16x4*)&xp[xaidx] = hv;
    if (kc < 7) v = *(const float4*)(arow + (kc + 1) * 32);
    bar_lds();
    bf16x8 bf = *(const bf16x8*)(PY + ((size_t)(kc * 64 + cg * 4 + w) * 64 + l) * 8);
    bf16x8 af0 = *(const bf16x8*)&xp[l * 8];
    bf16x8 af1 = *(const bf16x8*)&xp[512 + l * 8];
    acc0 = __builtin_amdgcn_mfma_f32_16x16x32_bf16(af0, bf, acc0, 0, 0, 0);
    acc1 = __builtin_amdgcn_mfma_f32_16x16x32_bf16(af1, bf, acc1, 0, 0, 0);
  }
  #pragma unroll
  for (int r = 0; r < 4; ++r) {
    TL[(q * 4 + r) * 68 + w * 16 + m15] = f2bf(acc0[r]);
    TL[(16 + q * 4 + r) * 68 + w * 16 + m15] = f2bf(acc1[r]);
  }
  bar_lds();
  const int ntL = tid >> 6, lane = tid & 63;
  const int kb = (lane >> 4) * 8, nl = ntL * 16 + (lane & 15);
  u16x8 o;
  #pragma unroll
  for (int j = 0; j < 8; ++j) o[j] = TL[(kb + j) * 68 + nl];
  *(u16x8*)(PWc + ((size_t)(rb * 64 + cg * 4 + ntL) * 64 + lane) * 8) = o;
}

// ---------------------------------------------------------------------------
// Main fused kernel (unchanged, verified round-3). 512 blocks x 512 threads.
// Frag layouts: A[m=lane&15][k=(lane>>4)*8+j], B[k=(lane>>4)*8+j][n=lane&15],
// D[row=(lane>>4)*4+r][col=lane&15]
// ---------------------------------------------------------------------------
__global__ __launch_bounds__(512, 4) void k_main(
    const float* __restrict__ x,
    const unsigned short* __restrict__ PGd, const unsigned short* __restrict__ PGg,
    const unsigned short* __restrict__ PW1, const unsigned short* __restrict__ PWc,
    const float* __restrict__ gdvA, const float* __restrict__ ggvA,
    const float* __restrict__ bdA, const float* __restrict__ bgA,
    const float* __restrict__ bd, const float* __restrict__ bg,
    const float* __restrict__ b1p, const float* __restrict__ bcomb,
    float* __restrict__ out) {
  __shared__ unsigned short XA[2][2048];       // 8KB  dbuf A-frag staging
  __shared__ unsigned short HBUF[16384];       // 32KB h1 / t as A-frags
  __shared__ float SMS[1024];                  // 4KB  LN partials
  __shared__ float MURS[128];                  // mu, rs per row
  __shared__ float OBUF[16 * 260];             // 16.6KB output staging tile

  const int tid = threadIdx.x;
  const int w = tid >> 6, l = tid & 63, q = l >> 4, m15 = l & 15;
  const int row0 = blockIdx.x * 64;

  float gdc[2], ggc[2], bdc[2], bgc[2], b1c[2];
  #pragma unroll
  for (int i = 0; i < 2; ++i) {
    int col = w * 32 + i * 16 + m15;
    gdc[i] = gdvA[col]; ggc[i] = ggvA[col];
    bdc[i] = bdA[col] + bd[col];
    bgc[i] = bgA[col] + bg[col];
    b1c[i] = b1p[col];
  }

  // ---------------- stage 1: [64,1024] @ (Gd|Gg) ------------------------------
  f32x4 accd[4][2], accg[4][2];
  const f32x4 zero4 = {0.f, 0.f, 0.f, 0.f};
  #pragma unroll
  for (int mt = 0; mt < 4; ++mt)
    #pragma unroll
    for (int i = 0; i < 2; ++i) { accd[mt][i] = zero4; accg[mt][i] = zero4; }

  const int srow = tid >> 3, sseg = tid & 7;
  const float* xrow = x + (size_t)(row0 + srow) * 1024 + sseg * 4;
  const int xaidx = (((srow >> 4) * 64 + (sseg >> 1) * 16 + (srow & 15)) << 3) + (sseg & 1) * 4;
  float ssum = 0.f, ssq = 0.f;

  float4 v = *(const float4*)xrow;
  for (int kc = 0; kc < 32; ++kc) {
    const int p = kc & 1;
    u16x4 hv; hv[0] = f2bf(v.x); hv[1] = f2bf(v.y); hv[2] = f2bf(v.z); hv[3] = f2bf(v.w);
    *(u16x4*)&XA[p][xaidx] = hv;
    ssum += v.x + v.y + v.z + v.w;
    ssq += v.x * v.x + v.y * v.y + v.z * v.z + v.w * v.w;
    if (kc < 31) v = *(const float4*)(xrow + (kc + 1) * 32);   // prefetch (survives bar_lds)
    bar_lds();
    bf16x8 fd[2], fg[2];
    #pragma unroll
    for (int i = 0; i < 2; ++i) {
      size_t off = ((size_t)(kc * 16 + w * 2 + i) * 64 + l) * 8;
      fd[i] = *(const bf16x8*)(PGd + off);
      fg[i] = *(const bf16x8*)(PGg + off);
    }
    #pragma unroll
    for (int mt = 0; mt < 4; ++mt) {
      bf16x8 af = *(const bf16x8*)&XA[p][(mt * 64 + l) * 8];
      #pragma unroll
      for (int i = 0; i < 2; ++i) {
        accd[mt][i] = __builtin_amdgcn_mfma_f32_16x16x32_bf16(af, fd[i], accd[mt][i], 0, 0, 0);
        accg[mt][i] = __builtin_amdgcn_mfma_f32_16x16x32_bf16(af, fg[i], accg[mt][i], 0, 0, 0);
      }
    }
  }

  // LN statistics (8 partials/row)
  SMS[tid] = ssum;
  SMS[512 + tid] = ssq;
  bar_lds();
  if (tid < 64) {
    float s = 0.f, sq = 0.f;
    #pragma unroll
    for (int p2 = 0; p2 < 8; ++p2) { s += SMS[tid * 8 + p2]; sq += SMS[512 + tid * 8 + p2]; }
    float mu = s * (1.f / 1024.f);
    float var = sq * (1.f / 1024.f) - mu * mu;
    MURS[tid * 2] = mu;
    MURS[tid * 2 + 1] = rsqrtf(var + LN_EPS);
  }
  bar_lds();

  // stage-1 epilogue: LN correction + GLU gate -> h1 bf16 in HBUF (A-frag order)
  #pragma unroll
  for (int i = 0; i < 2; ++i) {
    int q2 = i * 2 + (m15 >> 3), j2 = m15 & 7;
    #pragma unroll
    for (int mt = 0; mt < 4; ++mt) {
      #pragma unroll
      for (int r = 0; r < 4; ++r) {
        int row = mt * 16 + q * 4 + r;
        float mu = MURS[row * 2], rs = MURS[row * 2 + 1];
        float pd = rs * (accd[mt][i][r] - mu * gdc[i]) + bdc[i];
        float pg = rs * (accg[mt][i][r] - mu * ggc[i]) + bgc[i];
        float hv = pd / (1.f + __expf(-pg));
        HBUF[((mt * 8 + w) * 64 + q2 * 16 + q * 4 + r) * 8 + j2] = f2bf(hv);
      }
    }
  }
  bar_lds();

  // ---------------- stage 2: t = gelu(h1 @ W1' + b1') ------------------------
  f32x4 acc2[4][2];
  #pragma unroll
  for (int mt = 0; mt < 4; ++mt)
    #pragma unroll
    for (int i = 0; i < 2; ++i) acc2[mt][i] = zero4;
  for (int kc = 0; kc < 8; ++kc) {
    bf16x8 bf[2];
    #pragma unroll
    for (int i = 0; i < 2; ++i)
      bf[i] = *(const bf16x8*)(PW1 + ((size_t)(kc * 16 + w * 2 + i) * 64 + l) * 8);
    #pragma unroll
    for (int mt = 0; mt < 4; ++mt) {
      bf16x8 af = *(const bf16x8*)&HBUF[((mt * 8 + kc) * 64 + l) * 8];
      #pragma unroll
      for (int i = 0; i < 2; ++i)
        acc2[mt][i] = __builtin_amdgcn_mfma_f32_16x16x32_bf16(af, bf[i], acc2[mt][i], 0, 0, 0);
    }
  }
  bar_lds();   // all reads of h1 done before overwrite with t
  #pragma unroll
  for (int i = 0; i < 2; ++i) {
    int q2 = i * 2 + (m15 >> 3), j2 = m15 & 7;
    #pragma unroll
    for (int mt = 0; mt < 4; ++mt) {
      #pragma unroll
      for (int r = 0; r < 4; ++r) {
        float vv = acc2[mt][i][r] + b1c[i];
        float u = 0.7978845608f * (vv + 0.044715f * vv * vv * vv);
        float th = 1.f - 2.f / (1.f + __expf(2.f * u));
        HBUF[((mt * 8 + w) * 64 + q2 * 16 + q * 4 + r) * 8 + j2] = f2bf(0.5f * vv * (1.f + th));
      }
    }
  }
  bar_lds();

  // ---------------- stage 3: y = t @ Wcomb + bcomb; out = 0.5y + 0.5x --------
  for (int nc = 0; nc < 4; ++nc) {
    f32x4 acc3[4][2];
    #pragma unroll
    for (int mt = 0; mt < 4; ++mt)
      #pragma unroll
      for (int i = 0; i < 2; ++i) acc3[mt][i] = zero4;
    for (int kc = 0; kc < 8; ++kc) {
      bf16x8 bf[2];
      #pragma unroll
      for (int i = 0; i < 2; ++i)
        bf[i] = *(const bf16x8*)(PWc + ((size_t)(kc * 64 + nc * 16 + w * 2 + i) * 64 + l) * 8);
      #pragma unroll
      for (int mt = 0; mt < 4; ++mt) {
        bf16x8 af = *(const bf16x8*)&HBUF[((mt * 8 + kc) * 64 + l) * 8];
        #pragma unroll
        for (int i = 0; i < 2; ++i)
          acc3[mt][i] = __builtin_amdgcn_mfma_f32_16x16x32_bf16(af, bf[i], acc3[mt][i], 0, 0, 0);
      }
    }
    float bc[2];
    #pragma unroll
    for (int i = 0; i < 2; ++i) bc[i] = bcomb[nc * 256 + w * 32 + i * 16 + m15];
    // stage through OBUF per 16-row tile for coalesced float4 out writes
    const int rowL = tid >> 5, c0 = (tid & 31) * 4;
    #pragma unroll
    for (int mt = 0; mt < 4; ++mt) {
      #pragma unroll
      for (int r = 0; r < 4; ++r)
        #pragma unroll
        for (int i = 0; i < 2; ++i)
          OBUF[(q * 4 + r) * 260 + w * 32 + i * 16 + m15] = acc3[mt][i][r] + bc[i];
      bar_lds();
      const size_t gbase = (size_t)(row0 + mt * 16 + rowL) * 1024 + nc * 256;
      #pragma unroll
      for (int h = 0; h < 2; ++h) {
        int cc = c0 + h * 128;
        f32x4 yv = *(const f32x4*)&OBUF[rowL * 260 + cc];
        float4 xr = *(const float4*)(x + gbase + cc);
        float4 o;
        o.x = 0.5f * yv[0] + 0.5f * xr.x;
        o.y = 0.5f * yv[1] + 0.5f * xr.y;
        o.z = 0.5f * yv[2] + 0.5f * xr.z;
        o.w = 0.5f * yv[3] + 0.5f * xr.w;
        *(float4*)(out + gbase + cc) = o;
      }
      bar_lds();
    }
  }
}

// ---------------------------------------------------------------------------
extern "C" void kernel_launch(void* const* d_in, const int* in_sizes, int n_in,
                              void* d_out, int out_size, void* d_ws, size_t ws_size,
                              hipStream_t stream) {
  (void)in_sizes; (void)n_in; (void)out_size; (void)ws_size;
  const float* x    = (const float*)d_in[0];
  const float* ln_g = (const float*)d_in[1];
  const float* ln_b = (const float*)d_in[2];
  const float* Wd   = (const float*)d_in[3];
  const float* bd   = (const float*)d_in[4];
  const float* Wg   = (const float*)d_in[5];
  const float* bg   = (const float*)d_in[6];
  const float* dw_w = (const float*)d_in[7];
  const float* dw_b = (const float*)d_in[8];
  const float* W1   = (const float*)d_in[9];
  const float* b1   = (const float*)d_in[10];
  const float* W2   = (const float*)d_in[11];
  const float* b2   = (const float*)d_in[12];
  // d_in[13..16] = Wq,bq,Wk,bk : dead code (softmax over 1 key == 1)
  const float* Wv   = (const float*)d_in[17];
  const float* bv   = (const float*)d_in[18];
  const float* Wo   = (const float*)d_in[19];
  const float* bo   = (const float*)d_in[20];
  const float* Wu   = (const float*)d_in[21];
  const float* bu   = (const float*)d_in[22];
  const float* Wld  = (const float*)d_in[23];
  const float* Wlu  = (const float*)d_in[24];
  float* out = (float*)d_out;

  char* ws = (char*)d_ws;
  unsigned short* PGd = (unsigned short*)(ws + 0);         // 512KB
  unsigned short* PGg = (unsigned short*)(ws + 524288);    // 512KB
  unsigned short* PW1 = (unsigned short*)(ws + 1048576);   // 128KB
  unsigned short* PY  = (unsigned short*)(ws + 1310720);   // 512KB
  unsigned short* PWc = (unsigned short*)(ws + 1835008);   // 512KB
  float* X     = (float*)(ws + 2359296);                   // 256x256 f32, 256KB
  float* Y     = (float*)(ws + 2621440);                   // 256x1024 f32, 1MB
  float* GP    = (float*)(ws + 3670016);                   // 4x32x256 f32, 128KB
  float* gdvA  = (float*)(ws + 3801088);                   // 1KB
  float* ggvA  = (float*)(ws + 3802112);                   // 1KB
  float* bdA   = (float*)(ws + 3803136);                   // 1KB
  float* bgA   = (float*)(ws + 3804160);                   // 1KB
  float* b1p   = (float*)(ws + 3805184);                   // 1KB
  float* bcomb = (float*)(ws + 3806208);                   // 4KB -> ends 3810304

  hipLaunchKernelGGL(k_prep, dim3(154), dim3(256), 0, stream,
                     ln_g, ln_b, Wd, Wg, dw_w, dw_b, W1, b1, W2, b2,
                     Wv, bv, Wo, bo, Wu, bu, Wld, Wlu,
                     PGd, PGg, PW1, GP, b1p, X, Y, bcomb);
  hipLaunchKernelGGL(k_fold, dim3(65), dim3(256), 0, stream,
                     Y, Wld, Wlu, GP, PY, gdvA, ggvA, bdA, bgA);
  hipLaunchKernelGGL(k_wcomb, dim3(128), dim3(256), 0, stream, X, PY, PWc);
  hipLaunchKernelGGL(k_main, dim3(512), dim3(512), 0, stream,
                     x, PGd, PGg, PW1, PWc, gdvA, ggvA, bdA, bgA, bd, bg, b1p, bcomb, out);
}

// Round 5
// 404.246 us; speedup vs baseline: 1.2787x; 1.1314x over previous
//
#include <hip/hip_runtime.h>
#include <hip/hip_bf16.h>
#include <stdint.h>

// ---------------------------------------------------------------------------
// AdaptiveDecision fused kernel, MI355X / gfx950  (round 7)
//
// Math (per row, B=32768, C=1024, CH=256):
//   h  = LN(x); d = h@Wd+bd; g = h@Wg+bg; h1 = d*sigmoid(g)
//   h1 = h1*dw_w + dw_b                      (folded into W1)
//   t  = gelu_tanh(h1@W1'+b1')
//   y  = t@Wcomb + bcomb ;  out = 0.5*y + 0.5*x
//
// Binary-tree chain:  Wcomb = W2@Wv@Wo@Wu@(I+L) = X @ Y'''   (L = Wld@Wlu)
// Bias chain WITHOUT serial GEMV phases (round-6's 120us single-block stall):
//   r1 = b2@Wv + bv          (input-only, wide)
//   t0 = bo@Wu + bu          (input-only, wide)
//   r3 = r1@Y + t0  =>  bcomb = r3@(I+L) = r1@Y''' + t0@(I+L) = r1@Y3 + t1
// 3 launches (each ~25us of graph-node overhead saved per launch removed):
//   L1 k_prep  (133 blk): packs PGd/PGg/PW1 + colsum partials + b1p partials
//              + r1 + t0 + X=W2@Wv (f32) + merged Y-blocks: Y=Wo@Wu (VALU,
//              8 rows -> LDS) -> LoRA fold in-block -> PY frags + Y3 f32
//   L2 k_wcomb (130 blk): PWc = pack_bf16(X @ PY) via MFMA ;
//              bcomb = r1@Y3 + (t0 + (t0@Wld)@Wlu) ; GP/GPB reduces
//   L3 k_main  unchanged (verified round-3 kernel, ~134us).
// ---------------------------------------------------------------------------

typedef float f32x4 __attribute__((ext_vector_type(4)));
typedef __bf16 bf16x8 __attribute__((ext_vector_type(8)));
typedef unsigned short u16x8 __attribute__((ext_vector_type(8)));
typedef unsigned short u16x4 __attribute__((ext_vector_type(4)));

#define LN_EPS 1e-5f

__device__ __forceinline__ unsigned short f2bf(float f) {
  unsigned int u = __float_as_uint(f);
  u += 0x7fffu + ((u >> 16) & 1u);          // RNE
  return (unsigned short)(u >> 16);
}

// barrier that does NOT drain vmcnt: LDS-visibility only.
__device__ __forceinline__ void bar_lds() {
  asm volatile("s_waitcnt lgkmcnt(0)\n\ts_barrier" ::: "memory");
}

// ---------------------------------------------------------------------------
// L1: all input-only prep, one wide launch (133 blocks x 256 threads).
//  0-31  : pack ln_g.*Wd -> PGd  (+ GP colsum partial planes 0,1)
//  32-63 : pack ln_g.*Wg -> PGg  (+ GP planes 2,3)
//  64-71 : pack dw_w.*W1 -> PW1
//  72-79 : GPB[kc] partials of dw_b@W1 (k-split 32)
//  80    : r1 = b2@Wv + bv
//  81-84 : t0 = bo@Wu + bu          (4 x 256-col chunks)
//  85-100: X = W2@Wv  f32           (16 blocks x 16 rows, col=tid)
//  101-132: merged Y-blocks (32 x 8 rows): Y rows -> LDS; YL = Yslab@Wld;
//           Y''' = Y + YL@Wlu; write PY frags (bf16) + Y3 (f32)
// Packed B-frag layout: P[((kc*NT+nt)*64+lane)*8+j] = W[kc*32+(lane>>4)*8+j][nt*16+(lane&15)]
// ---------------------------------------------------------------------------
__global__ __launch_bounds__(256) void k_prep(
    const float* __restrict__ ln_g, const float* __restrict__ ln_b,
    const float* __restrict__ Wd, const float* __restrict__ Wg,
    const float* __restrict__ dw_w, const float* __restrict__ dw_b,
    const float* __restrict__ W1,
    const float* __restrict__ W2, const float* __restrict__ b2,
    const float* __restrict__ Wv, const float* __restrict__ bv,
    const float* __restrict__ Wo, const float* __restrict__ bo,
    const float* __restrict__ Wu, const float* __restrict__ bu,
    const float* __restrict__ Wld, const float* __restrict__ Wlu,
    unsigned short* __restrict__ PGd, unsigned short* __restrict__ PGg,
    unsigned short* __restrict__ PW1, float* __restrict__ GP,
    float* __restrict__ GPB, float* __restrict__ r1,
    float* __restrict__ t0, float* __restrict__ X,
    unsigned short* __restrict__ PY, float* __restrict__ Y3) {
  __shared__ alignas(16) char SMEM[49664];
  const int b = blockIdx.x, tid = threadIdx.x;

  if (b < 72) {
    // ---- pack one 32-row K-chunk of a 256-col weight into B-frag layout ----
    float (*S)[257] = (float(*)[257])SMEM;      // 32x257 f = 32896B
    const float* src; const float* scale; unsigned short* dst;
    int kc; int gpa = -1;
    if (b < 32)      { src = Wd; scale = ln_g; dst = PGd; kc = b;      gpa = 0; }
    else if (b < 64) { src = Wg; scale = ln_g; dst = PGg; kc = b - 32; gpa = 2; }
    else             { src = W1; scale = dw_w; dst = PW1; kc = b - 64; }
    float csg = 0.f, csb = 0.f;
    for (int r = 0; r < 32; ++r) {
      int k = kc * 32 + r;
      float raw = src[(size_t)k * 256 + tid];
      float v = scale[k] * raw;
      S[r][tid] = v;
      if (gpa >= 0) { csg += v; csb += ln_b[k] * raw; }
    }
    if (gpa >= 0) {
      GP[((size_t)gpa * 32 + kc) * 256 + tid] = csg;
      GP[((size_t)(gpa + 1) * 32 + kc) * 256 + tid] = csb;
    }
    __syncthreads();
    const int ntL = tid >> 4;
    #pragma unroll
    for (int c = 0; c < 4; ++c) {
      int lane = (tid * 4 + c) & 63;
      int kb = (lane >> 4) * 8, nl = ntL * 16 + (lane & 15);
      u16x8 o;
      #pragma unroll
      for (int j = 0; j < 8; ++j) o[j] = f2bf(S[kb + j][nl]);
      *(u16x8*)(dst + ((size_t)(kc * 16 + ntL) * 64 + lane) * 8) = o;
    }
  } else if (b < 80) {
    // ---- GPB partials for b1p (k-split) ----
    const int kc = b - 72;
    float s = 0.f;
    #pragma unroll
    for (int k = 0; k < 32; ++k)
      s += dw_b[kc * 32 + k] * W1[(size_t)(kc * 32 + k) * 256 + tid];
    GPB[(size_t)kc * 256 + tid] = s;
  } else if (b == 80) {
    // ---- r1 = b2@Wv + bv ----
    float s = bv[tid];
    #pragma unroll 8
    for (int k = 0; k < 256; ++k) s += b2[k] * Wv[(size_t)k * 256 + tid];
    r1[tid] = s;
  } else if (b < 85) {
    // ---- t0 chunk: t0 = bo@Wu + bu ----
    const int c0 = (b - 81) * 256;
    float s = bu[c0 + tid];
    #pragma unroll 8
    for (int k = 0; k < 256; ++k) s += bo[k] * Wu[(size_t)k * 1024 + c0 + tid];
    t0[c0 + tid] = s;
  } else if (b < 101) {
    // ---- X = W2@Wv (16 rows/block, col=tid; W2 reads are block-uniform) ----
    const int r0 = (b - 85) * 16;
    float acc[16];
    #pragma unroll
    for (int r = 0; r < 16; ++r) acc[r] = 0.f;
    #pragma unroll 4
    for (int n = 0; n < 256; ++n) {
      float wv = Wv[(size_t)n * 256 + tid];
      #pragma unroll
      for (int r = 0; r < 16; ++r) acc[r] += W2[(size_t)(r0 + r) * 256 + n] * wv;
    }
    #pragma unroll
    for (int r = 0; r < 16; ++r) X[(size_t)(r0 + r) * 256 + tid] = acc[r];
  } else {
    // ---- merged Y-block: 8 rows of Y=Wo@Wu, LoRA fold, PY + Y3 ----
    float* YS = (float*)SMEM;                   // [8][1024]  32KB
    float* PART = (float*)(SMEM + 32768);       // [8*16][32] 16KB
    float* YL = (float*)(SMEM + 49152);         // [8][16]    512B
    const int rb = b - 101;                     // 0..31
    const int r0 = rb * 8;
    const int c0 = tid * 4;
    // phase 0: Y rows (VALU outer-product; Wo reads block-uniform -> s_load)
    f32x4 acc[8];
    #pragma unroll
    for (int r = 0; r < 8; ++r) acc[r] = (f32x4){0.f, 0.f, 0.f, 0.f};
    #pragma unroll 4
    for (int k = 0; k < 256; ++k) {
      f32x4 wu = *(const f32x4*)(Wu + (size_t)k * 1024 + c0);
      #pragma unroll
      for (int r = 0; r < 8; ++r) {
        float wo = Wo[(size_t)(r0 + r) * 256 + k];
        #pragma unroll
        for (int j = 0; j < 4; ++j) acc[r][j] += wo * wu[j];
      }
    }
    #pragma unroll
    for (int r = 0; r < 8; ++r) *(f32x4*)&YS[r * 1024 + c0] = acc[r];
    __syncthreads();
    // phase A: YL[8][16] = Yslab @ Wld   (n split over 32 lanes, coalesced)
    {
      const int r = tid >> 5, g = tid & 31;
      float p[16];
      #pragma unroll
      for (int s = 0; s < 16; ++s) p[s] = 0.f;
      for (int i = 0; i < 32; ++i) {
        int n = g + i * 32;
        float yv = YS[r * 1024 + n];
        const float* wl = Wld + (size_t)n * 16;
        #pragma unroll
        for (int s = 0; s < 16; ++s) p[s] += yv * wl[s];
      }
      #pragma unroll
      for (int s = 0; s < 16; ++s) PART[(r * 16 + s) * 32 + g] = p[s];
    }
    __syncthreads();
    if (tid < 128) {
      float s = 0.f;
      #pragma unroll
      for (int g = 0; g < 32; ++g) s += PART[tid * 32 + g];
      YL[tid] = s;
    }
    __syncthreads();
    // phase B: y3 = YS + YL@Wlu ; write Y3 f32 + PY frags
    f32x4 y3[8];
    #pragma unroll
    for (int r = 0; r < 8; ++r) y3[r] = *(const f32x4*)&YS[r * 1024 + c0];
    #pragma unroll
    for (int s = 0; s < 16; ++s) {
      f32x4 wl = *(const f32x4*)(Wlu + (size_t)s * 1024 + c0);
      #pragma unroll
      for (int r = 0; r < 8; ++r) {
        float m = YL[r * 16 + s];
        #pragma unroll
        for (int j = 0; j < 4; ++j) y3[r][j] += m * wl[j];
      }
    }
    #pragma unroll
    for (int r = 0; r < 8; ++r)
      *(f32x4*)(Y3 + (size_t)(r0 + r) * 1024 + c0) = y3[r];
    // PY: P[((kc*64+nt)*64+lane)*8+j] = Y'''[kc*32+(lane>>4)*8+j][nt*16+(lane&15)]
    // our 8 rows cover lane>>4 == rb&3, j == local row.
    const int kc = rb >> 2, a = rb & 3;
    #pragma unroll
    for (int j2 = 0; j2 < 4; ++j2) {
      int c = c0 + j2;
      int nt = c >> 4, lane = a * 16 + (c & 15);
      u16x8 o;
      #pragma unroll
      for (int j = 0; j < 8; ++j) o[j] = f2bf(y3[j][j2]);
      *(u16x8*)(PY + ((size_t)(kc * 64 + nt) * 64 + lane) * 8) = o;
    }
  }
}

// ---------------------------------------------------------------------------
// L2: k_wcomb (130 blocks):
//  0-127: PWc = pack_bf16(X @ PY)  (MFMA, 32 rows x 64 cols per block)
//  128  : bcomb = r1@Y3 + (t0 + (t0@Wld)@Wlu)
//  129  : reduce GP -> gdvA/bdA/ggvA/bgA ; GPB+b1 -> b1p
// ---------------------------------------------------------------------------
__global__ __launch_bounds__(256) void k_wcomb(
    const float* __restrict__ X, const unsigned short* __restrict__ PY,
    unsigned short* __restrict__ PWc,
    const float* __restrict__ r1, const float* __restrict__ t0,
    const float* __restrict__ Wld, const float* __restrict__ Wlu,
    const float* __restrict__ Y3, const float* __restrict__ GP,
    const float* __restrict__ GPB, const float* __restrict__ b1,
    float* __restrict__ gdvA, float* __restrict__ ggvA,
    float* __restrict__ bdA, float* __restrict__ bgA,
    float* __restrict__ b1p, float* __restrict__ bcomb) {
  __shared__ alignas(16) char SMEM[32896];
  const int b = blockIdx.x, tid = threadIdx.x;
  if (b < 128) {
    unsigned short* XA2 = (unsigned short*)SMEM;      // 2 x 1024 u16 dbuf
    unsigned short* TL = XA2 + 2048;                  // 32x68 u16
    const int rb = b >> 4, cg = b & 15;
    const int w = tid >> 6, l = tid & 63, q = l >> 4, m15 = l & 15;
    const int r0 = rb * 32;
    const int srow = tid >> 3;                        // 0..31
    const int kk = (tid & 7) * 4;                     // 0,4,..,28
    const int rt = srow >> 4, m = srow & 15;
    const int xaidx = rt * 512 + ((kk >> 3) * 16 + m) * 8 + (kk & 7);
    const float* arow = X + (size_t)(r0 + srow) * 256 + kk;
    f32x4 acc0 = {0.f, 0.f, 0.f, 0.f}, acc1 = {0.f, 0.f, 0.f, 0.f};
    float4 v = *(const float4*)arow;
    for (int kc = 0; kc < 8; ++kc) {
      unsigned short* xp = XA2 + (kc & 1) * 1024;
      u16x4 hv; hv[0] = f2bf(v.x); hv[1] = f2bf(v.y); hv[2] = f2bf(v.z); hv[3] = f2bf(v.w);
      *(u16x4*)&xp[xaidx] = hv;
      if (kc < 7) v = *(const float4*)(arow + (kc + 1) * 32);
      bar_lds();
      bf16x8 bf = *(const bf16x8*)(PY + ((size_t)(kc * 64 + cg * 4 + w) * 64 + l) * 8);
      bf16x8 af0 = *(const bf16x8*)&xp[l * 8];
      bf16x8 af1 = *(const bf16x8*)&xp[512 + l * 8];
      acc0 = __builtin_amdgcn_mfma_f32_16x16x32_bf16(af0, bf, acc0, 0, 0, 0);
      acc1 = __builtin_amdgcn_mfma_f32_16x16x32_bf16(af1, bf, acc1, 0, 0, 0);
    }
    #pragma unroll
    for (int r = 0; r < 4; ++r) {
      TL[(q * 4 + r) * 68 + w * 16 + m15] = f2bf(acc0[r]);
      TL[(16 + q * 4 + r) * 68 + w * 16 + m15] = f2bf(acc1[r]);
    }
    bar_lds();
    const int ntL = tid >> 6, lane = tid & 63;
    const int kb = (lane >> 4) * 8, nl = ntL * 16 + (lane & 15);
    u16x8 o;
    #pragma unroll
    for (int j = 0; j < 8; ++j) o[j] = TL[(kb + j) * 68 + nl];
    *(u16x8*)(PWc + ((size_t)(rb * 64 + cg * 4 + ntL) * 64 + lane) * 8) = o;
  } else if (b == 128) {
    // bcomb = r1@Y3 + t1 ; t1 = t0 + (t0@Wld)@Wlu
    float* F = (float*)SMEM;
    float* R1 = F;            // 256
    float* T0 = F + 256;      // 1024
    float* PART = F + 1280;   // 256
    float* U16 = F + 1536;    // 16
    R1[tid] = r1[tid];
    #pragma unroll
    for (int c2 = 0; c2 < 4; ++c2) T0[tid + c2 * 256] = t0[tid + c2 * 256];
    __syncthreads();
    {
      const int g = tid >> 4, s = tid & 15;
      float p = 0.f;
      #pragma unroll 4
      for (int n = g * 64; n < g * 64 + 64; ++n) p += T0[n] * Wld[(size_t)n * 16 + s];
      PART[g * 16 + s] = p;
    }
    __syncthreads();
    if (tid < 16) {
      float s = 0.f;
      #pragma unroll
      for (int g = 0; g < 16; ++g) s += PART[g * 16 + tid];
      U16[tid] = s;
    }
    __syncthreads();
    const int c0 = tid * 4;
    f32x4 rv = {0.f, 0.f, 0.f, 0.f};
    #pragma unroll 4
    for (int k = 0; k < 256; ++k) {
      f32x4 yv = *(const f32x4*)(Y3 + (size_t)k * 1024 + c0);
      float rk = R1[k];
      #pragma unroll
      for (int j = 0; j < 4; ++j) rv[j] += rk * yv[j];
    }
    f32x4 vv;
    #pragma unroll
    for (int j = 0; j < 4; ++j) vv[j] = T0[c0 + j] + rv[j];
    #pragma unroll
    for (int s = 0; s < 16; ++s) {
      f32x4 wl = *(const f32x4*)(Wlu + (size_t)s * 1024 + c0);
      #pragma unroll
      for (int j = 0; j < 4; ++j) vv[j] += U16[s] * wl[j];
    }
    *(f32x4*)(bcomb + c0) = vv;
  } else {
    // reduces: GP colsum planes ; GPB + b1 -> b1p
    float s0 = 0.f, s1 = 0.f, s2 = 0.f, s3 = 0.f;
    for (int kc2 = 0; kc2 < 32; ++kc2) {
      s0 += GP[((size_t)0 * 32 + kc2) * 256 + tid];
      s1 += GP[((size_t)1 * 32 + kc2) * 256 + tid];
      s2 += GP[((size_t)2 * 32 + kc2) * 256 + tid];
      s3 += GP[((size_t)3 * 32 + kc2) * 256 + tid];
    }
    gdvA[tid] = s0; bdA[tid] = s1; ggvA[tid] = s2; bgA[tid] = s3;
    float sb1 = b1[tid];
    #pragma unroll
    for (int p = 0; p < 8; ++p) sb1 += GPB[(size_t)p * 256 + tid];
    b1p[tid] = sb1;
  }
}

// ---------------------------------------------------------------------------
// Main fused kernel (unchanged, verified round-3). 512 blocks x 512 threads.
// Frag layouts: A[m=lane&15][k=(lane>>4)*8+j], B[k=(lane>>4)*8+j][n=lane&15],
// D[row=(lane>>4)*4+r][col=lane&15]
// ---------------------------------------------------------------------------
__global__ __launch_bounds__(512, 4) void k_main(
    const float* __restrict__ x,
    const unsigned short* __restrict__ PGd, const unsigned short* __restrict__ PGg,
    const unsigned short* __restrict__ PW1, const unsigned short* __restrict__ PWc,
    const float* __restrict__ gdvA, const float* __restrict__ ggvA,
    const float* __restrict__ bdA, const float* __restrict__ bgA,
    const float* __restrict__ bd, const float* __restrict__ bg,
    const float* __restrict__ b1p, const float* __restrict__ bcomb,
    float* __restrict__ out) {
  __shared__ unsigned short XA[2][2048];       // 8KB  dbuf A-frag staging
  __shared__ unsigned short HBUF[16384];       // 32KB h1 / t as A-frags
  __shared__ float SMS[1024];                  // 4KB  LN partials
  __shared__ float MURS[128];                  // mu, rs per row
  __shared__ float OBUF[16 * 260];             // 16.6KB output staging tile

  const int tid = threadIdx.x;
  const int w = tid >> 6, l = tid & 63, q = l >> 4, m15 = l & 15;
  const int row0 = blockIdx.x * 64;

  float gdc[2], ggc[2], bdc[2], bgc[2], b1c[2];
  #pragma unroll
  for (int i = 0; i < 2; ++i) {
    int col = w * 32 + i * 16 + m15;
    gdc[i] = gdvA[col]; ggc[i] = ggvA[col];
    bdc[i] = bdA[col] + bd[col];
    bgc[i] = bgA[col] + bg[col];
    b1c[i] = b1p[col];
  }

  // ---------------- stage 1: [64,1024] @ (Gd|Gg) ------------------------------
  f32x4 accd[4][2], accg[4][2];
  const f32x4 zero4 = {0.f, 0.f, 0.f, 0.f};
  #pragma unroll
  for (int mt = 0; mt < 4; ++mt)
    #pragma unroll
    for (int i = 0; i < 2; ++i) { accd[mt][i] = zero4; accg[mt][i] = zero4; }

  const int srow = tid >> 3, sseg = tid & 7;
  const float* xrow = x + (size_t)(row0 + srow) * 1024 + sseg * 4;
  const int xaidx = (((srow >> 4) * 64 + (sseg >> 1) * 16 + (srow & 15)) << 3) + (sseg & 1) * 4;
  float ssum = 0.f, ssq = 0.f;

  float4 v = *(const float4*)xrow;
  for (int kc = 0; kc < 32; ++kc) {
    const int p = kc & 1;
    u16x4 hv; hv[0] = f2bf(v.x); hv[1] = f2bf(v.y); hv[2] = f2bf(v.z); hv[3] = f2bf(v.w);
    *(u16x4*)&XA[p][xaidx] = hv;
    ssum += v.x + v.y + v.z + v.w;
    ssq += v.x * v.x + v.y * v.y + v.z * v.z + v.w * v.w;
    if (kc < 31) v = *(const float4*)(xrow + (kc + 1) * 32);   // prefetch (survives bar_lds)
    bar_lds();
    bf16x8 fd[2], fg[2];
    #pragma unroll
    for (int i = 0; i < 2; ++i) {
      size_t off = ((size_t)(kc * 16 + w * 2 + i) * 64 + l) * 8;
      fd[i] = *(const bf16x8*)(PGd + off);
      fg[i] = *(const bf16x8*)(PGg + off);
    }
    #pragma unroll
    for (int mt = 0; mt < 4; ++mt) {
      bf16x8 af = *(const bf16x8*)&XA[p][(mt * 64 + l) * 8];
      #pragma unroll
      for (int i = 0; i < 2; ++i) {
        accd[mt][i] = __builtin_amdgcn_mfma_f32_16x16x32_bf16(af, fd[i], accd[mt][i], 0, 0, 0);
        accg[mt][i] = __builtin_amdgcn_mfma_f32_16x16x32_bf16(af, fg[i], accg[mt][i], 0, 0, 0);
      }
    }
  }

  // LN statistics (8 partials/row)
  SMS[tid] = ssum;
  SMS[512 + tid] = ssq;
  bar_lds();
  if (tid < 64) {
    float s = 0.f, sq = 0.f;
    #pragma unroll
    for (int p2 = 0; p2 < 8; ++p2) { s += SMS[tid * 8 + p2]; sq += SMS[512 + tid * 8 + p2]; }
    float mu = s * (1.f / 1024.f);
    float var = sq * (1.f / 1024.f) - mu * mu;
    MURS[tid * 2] = mu;
    MURS[tid * 2 + 1] = rsqrtf(var + LN_EPS);
  }
  bar_lds();

  // stage-1 epilogue: LN correction + GLU gate -> h1 bf16 in HBUF (A-frag order)
  #pragma unroll
  for (int i = 0; i < 2; ++i) {
    int q2 = i * 2 + (m15 >> 3), j2 = m15 & 7;
    #pragma unroll
    for (int mt = 0; mt < 4; ++mt) {
      #pragma unroll
      for (int r = 0; r < 4; ++r) {
        int row = mt * 16 + q * 4 + r;
        float mu = MURS[row * 2], rs = MURS[row * 2 + 1];
        float pd = rs * (accd[mt][i][r] - mu * gdc[i]) + bdc[i];
        float pg = rs * (accg[mt][i][r] - mu * ggc[i]) + bgc[i];
        float hv = pd / (1.f + __expf(-pg));
        HBUF[((mt * 8 + w) * 64 + q2 * 16 + q * 4 + r) * 8 + j2] = f2bf(hv);
      }
    }
  }
  bar_lds();

  // ---------------- stage 2: t = gelu(h1 @ W1' + b1') ------------------------
  f32x4 acc2[4][2];
  #pragma unroll
  for (int mt = 0; mt < 4; ++mt)
    #pragma unroll
    for (int i = 0; i < 2; ++i) acc2[mt][i] = zero4;
  for (int kc = 0; kc < 8; ++kc) {
    bf16x8 bf[2];
    #pragma unroll
    for (int i = 0; i < 2; ++i)
      bf[i] = *(const bf16x8*)(PW1 + ((size_t)(kc * 16 + w * 2 + i) * 64 + l) * 8);
    #pragma unroll
    for (int mt = 0; mt < 4; ++mt) {
      bf16x8 af = *(const bf16x8*)&HBUF[((mt * 8 + kc) * 64 + l) * 8];
      #pragma unroll
      for (int i = 0; i < 2; ++i)
        acc2[mt][i] = __builtin_amdgcn_mfma_f32_16x16x32_bf16(af, bf[i], acc2[mt][i], 0, 0, 0);
    }
  }
  bar_lds();   // all reads of h1 done before overwrite with t
  #pragma unroll
  for (int i = 0; i < 2; ++i) {
    int q2 = i * 2 + (m15 >> 3), j2 = m15 & 7;
    #pragma unroll
    for (int mt = 0; mt < 4; ++mt) {
      #pragma unroll
      for (int r = 0; r < 4; ++r) {
        float vv = acc2[mt][i][r] + b1c[i];
        float u = 0.7978845608f * (vv + 0.044715f * vv * vv * vv);
        float th = 1.f - 2.f / (1.f + __expf(2.f * u));
        HBUF[((mt * 8 + w) * 64 + q2 * 16 + q * 4 + r) * 8 + j2] = f2bf(0.5f * vv * (1.f + th));
      }
    }
  }
  bar_lds();

  // ---------------- stage 3: y = t @ Wcomb + bcomb; out = 0.5y + 0.5x --------
  for (int nc = 0; nc < 4; ++nc) {
    f32x4 acc3[4][2];
    #pragma unroll
    for (int mt = 0; mt < 4; ++mt)
      #pragma unroll
      for (int i = 0; i < 2; ++i) acc3[mt][i] = zero4;
    for (int kc = 0; kc < 8; ++kc) {
      bf16x8 bf[2];
      #pragma unroll
      for (int i = 0; i < 2; ++i)
        bf[i] = *(const bf16x8*)(PWc + ((size_t)(kc * 64 + nc * 16 + w * 2 + i) * 64 + l) * 8);
      #pragma unroll
      for (int mt = 0; mt < 4; ++mt) {
        bf16x8 af = *(const bf16x8*)&HBUF[((mt * 8 + kc) * 64 + l) * 8];
        #pragma unroll
        for (int i = 0; i < 2; ++i)
          acc3[mt][i] = __builtin_amdgcn_mfma_f32_16x16x32_bf16(af, bf[i], acc3[mt][i], 0, 0, 0);
      }
    }
    float bc[2];
    #pragma unroll
    for (int i = 0; i < 2; ++i) bc[i] = bcomb[nc * 256 + w * 32 + i * 16 + m15];
    // stage through OBUF per 16-row tile for coalesced float4 out writes
    const int rowL = tid >> 5, c0 = (tid & 31) * 4;
    #pragma unroll
    for (int mt = 0; mt < 4; ++mt) {
      #pragma unroll
      for (int r = 0; r < 4; ++r)
        #pragma unroll
        for (int i = 0; i < 2; ++i)
          OBUF[(q * 4 + r) * 260 + w * 32 + i * 16 + m15] = acc3[mt][i][r] + bc[i];
      bar_lds();
      const size_t gbase = (size_t)(row0 + mt * 16 + rowL) * 1024 + nc * 256;
      #pragma unroll
      for (int h = 0; h < 2; ++h) {
        int cc = c0 + h * 128;
        f32x4 yv = *(const f32x4*)&OBUF[rowL * 260 + cc];
        float4 xr = *(const float4*)(x + gbase + cc);
        float4 o;
        o.x = 0.5f * yv[0] + 0.5f * xr.x;
        o.y = 0.5f * yv[1] + 0.5f * xr.y;
        o.z = 0.5f * yv[2] + 0.5f * xr.z;
        o.w = 0.5f * yv[3] + 0.5f * xr.w;
        *(float4*)(out + gbase + cc) = o;
      }
      bar_lds();
    }
  }
}

// ---------------------------------------------------------------------------
extern "C" void kernel_launch(void* const* d_in, const int* in_sizes, int n_in,
                              void* d_out, int out_size, void* d_ws, size_t ws_size,
                              hipStream_t stream) {
  (void)in_sizes; (void)n_in; (void)out_size; (void)ws_size;
  const float* x    = (const float*)d_in[0];
  const float* ln_g = (const float*)d_in[1];
  const float* ln_b = (const float*)d_in[2];
  const float* Wd   = (const float*)d_in[3];
  const float* bd   = (const float*)d_in[4];
  const float* Wg   = (const float*)d_in[5];
  const float* bg   = (const float*)d_in[6];
  const float* dw_w = (const float*)d_in[7];
  const float* dw_b = (const float*)d_in[8];
  const float* W1   = (const float*)d_in[9];
  const float* b1   = (const float*)d_in[10];
  const float* W2   = (const float*)d_in[11];
  const float* b2   = (const float*)d_in[12];
  // d_in[13..16] = Wq,bq,Wk,bk : dead code (softmax over 1 key == 1)
  const float* Wv   = (const float*)d_in[17];
  const float* bv   = (const float*)d_in[18];
  const float* Wo   = (const float*)d_in[19];
  const float* bo   = (const float*)d_in[20];
  const float* Wu   = (const float*)d_in[21];
  const float* bu   = (const float*)d_in[22];
  const float* Wld  = (const float*)d_in[23];
  const float* Wlu  = (const float*)d_in[24];
  float* out = (float*)d_out;

  char* ws = (char*)d_ws;
  unsigned short* PGd = (unsigned short*)(ws + 0);         // 512KB
  unsigned short* PGg = (unsigned short*)(ws + 524288);    // 512KB
  unsigned short* PW1 = (unsigned short*)(ws + 1048576);   // 128KB
  unsigned short* PY  = (unsigned short*)(ws + 1310720);   // 512KB
  unsigned short* PWc = (unsigned short*)(ws + 1835008);   // 512KB
  float* X     = (float*)(ws + 2359296);                   // 256x256 f32, 256KB
  float* Y3    = (float*)(ws + 2621440);                   // 256x1024 f32, 1MB
  float* GP    = (float*)(ws + 3670016);                   // 4x32x256 f32, 128KB
  float* gdvA  = (float*)(ws + 3801088);                   // 1KB
  float* ggvA  = (float*)(ws + 3802112);                   // 1KB
  float* bdA   = (float*)(ws + 3803136);                   // 1KB
  float* bgA   = (float*)(ws + 3804160);                   // 1KB
  float* b1p   = (float*)(ws + 3805184);                   // 1KB
  float* bcomb = (float*)(ws + 3806208);                   // 4KB
  float* r1    = (float*)(ws + 3810304);                   // 1KB
  float* t0    = (float*)(ws + 3811328);                   // 4KB
  float* GPB   = (float*)(ws + 3815424);                   // 8x256 f32, 8KB -> 3823616

  hipLaunchKernelGGL(k_prep, dim3(133), dim3(256), 0, stream,
                     ln_g, ln_b, Wd, Wg, dw_w, dw_b, W1, W2, b2,
                     Wv, bv, Wo, bo, Wu, bu, Wld, Wlu,
                     PGd, PGg, PW1, GP, GPB, r1, t0, X, PY, Y3);
  hipLaunchKernelGGL(k_wcomb, dim3(130), dim3(256), 0, stream,
                     X, PY, PWc, r1, t0, Wld, Wlu, Y3, GP, GPB, b1,
                     gdvA, ggvA, bdA, bgA, b1p, bcomb);
  hipLaunchKernelGGL(k_main, dim3(512), dim3(512), 0, stream,
                     x, PGd, PGg, PW1, PWc, gdvA, ggvA, bdA, bgA, bd, bg, b1p, bcomb, out);
}